// Round 2
// baseline (5582.018 us; speedup 1.0000x reference)
//
#include <hip/hip_runtime.h>

#define T_  512
#define B_  128
#define D_  512
#define H_  512
#define N4H 2048

typedef _Float16 half8  __attribute__((ext_vector_type(8)));
typedef _Float16 half4v __attribute__((ext_vector_type(4)));
typedef float    f32x4  __attribute__((ext_vector_type(4)));

// ---------- converts ----------
__global__ void cvt_ins(const float* __restrict__ in, _Float16* __restrict__ out) {
    int i = blockIdx.x * 256 + threadIdx.x;            // group of 4 elems
    float4 v = ((const float4*)in)[i];
    half4v o;
    o[0] = (_Float16)v.x; o[1] = (_Float16)v.y;
    o[2] = (_Float16)v.z; o[3] = (_Float16)v.w;
    ((half4v*)out)[i] = o;
}

__global__ void cvt_wi(const float* __restrict__ Wi, _Float16* __restrict__ WiT) {
    int i = blockIdx.x * 256 + threadIdx.x;            // over 512*2048
    int k = i >> 11, n = i & 2047;
    WiT[n * D_ + k] = (_Float16)Wi[i];                 // transpose: [N][K]
}

// WhP[((k2*512 + j)*8) + g*2 + p] = Wh[(2*k2+p)*2048 + g*512 + j]
__global__ void cvt_wh(const float* __restrict__ Wh, _Float16* __restrict__ WhP) {
    int i = blockIdx.x * 256 + threadIdx.x;            // over 512*2048
    int k = i >> 11, n = i & 2047;
    int g = n >> 9, j = n & 511;
    WhP[((((k >> 1) * 512 + j) << 3)) + (g << 1) + (k & 1)] = (_Float16)Wh[i];
}

// ---------- phase 1: Z = X @ WiT^T  (f16 in, f32 acc, f16 out) ----------
__global__ __launch_bounds__(256) void gemm_xwi(const _Float16* __restrict__ X,
                                                const _Float16* __restrict__ WT,
                                                _Float16* __restrict__ Z) {
    __shared__ _Float16 As[128 * 32];
    __shared__ _Float16 Bs[128 * 32];
    const int tid  = threadIdx.x;
    const int lane = tid & 63;
    const int wid  = tid >> 6;
    const int wm   = wid >> 1, wn = wid & 1;
    const int bm   = blockIdx.x, bn = blockIdx.y;

    f32x4 acc[4][4];
    #pragma unroll
    for (int m = 0; m < 4; ++m)
        #pragma unroll
        for (int n = 0; n < 4; ++n)
            acc[m][n] = (f32x4){0.f, 0.f, 0.f, 0.f};

    const _Float16* Xb = X  + (size_t)bm * 128 * D_;
    const _Float16* Wb = WT + (size_t)bn * 128 * D_;

    for (int kt = 0; kt < D_ / 32; ++kt) {
        if (kt) __syncthreads();
        #pragma unroll
        for (int s = 0; s < 2; ++s) {
            int idx = tid + s * 256;                   // 0..511
            int row = idx >> 2, cg = idx & 3;
            *(half8*)&As[idx * 8] = *(const half8*)&Xb[row * D_ + kt * 32 + cg * 8];
            *(half8*)&Bs[idx * 8] = *(const half8*)&Wb[row * D_ + kt * 32 + cg * 8];
        }
        __syncthreads();
        half8 a[4], b[4];
        #pragma unroll
        for (int m = 0; m < 4; ++m)
            a[m] = *(const half8*)&As[(wm * 64 + m * 16 + (lane & 15)) * 32 + (lane >> 4) * 8];
        #pragma unroll
        for (int n = 0; n < 4; ++n)
            b[n] = *(const half8*)&Bs[(wn * 64 + n * 16 + (lane & 15)) * 32 + (lane >> 4) * 8];
        #pragma unroll
        for (int m = 0; m < 4; ++m)
            #pragma unroll
            for (int n = 0; n < 4; ++n)
                acc[m][n] = __builtin_amdgcn_mfma_f32_16x16x32_f16(a[m], b[n], acc[m][n], 0, 0, 0);
    }

    const int row0 = bm * 128 + wm * 64;
    const int col0 = bn * 128 + wn * 64;
    #pragma unroll
    for (int m = 0; m < 4; ++m)
        #pragma unroll
        for (int n = 0; n < 4; ++n)
            #pragma unroll
            for (int e = 0; e < 4; ++e) {
                int r = row0 + m * 16 + (lane >> 4) * 4 + e;
                int c = col0 + n * 16 + (lane & 15);
                Z[(size_t)r * N4H + c] = (_Float16)acc[m][n][e];
            }
}

// ---------- phase 2: sequential scan, one block per batch row ----------
__global__ __launch_bounds__(512) void lstm_scan(const _Float16* __restrict__ Z,
                                                 const _Float16* __restrict__ WhP,
                                                 const float* __restrict__ bv,
                                                 const int* __restrict__ resets,
                                                 const float* __restrict__ c0,
                                                 const float* __restrict__ h0,
                                                 float* __restrict__ out) {
    const int b = blockIdx.x;
    const int j = threadIdx.x;
    __shared__ float hs[H_];

    float c = c0[b * H_ + j];
    hs[j] = h0[b * H_ + j];
    const float b0 = bv[j], b1 = bv[H_ + j], b2 = bv[2 * H_ + j], b3 = bv[3 * H_ + j];
    float* ys = out + 2 * B_ * H_;

    const half8* wp = (const half8*)WhP + j;           // + k2*512 per step of k2

    for (int t = 0; t < T_; ++t) {
        __syncthreads();                                // hs (h_{t-1}) visible
        const bool rst = resets[t * B_ + b] != 0;       // block-uniform (int32!)
        const _Float16* zr = Z + ((size_t)(t * B_ + b)) * N4H;
        float z0 = b0 + (float)zr[j];
        float z1 = b1 + (float)zr[H_ + j];
        float z2 = b2 + (float)zr[2 * H_ + j];
        float z3 = b3 + (float)zr[3 * H_ + j];
        if (rst) {
            c = 0.f;                                    // h-part contributes 0; skip dot
        } else {
            #pragma unroll 8
            for (int k2 = 0; k2 < H_ / 2; ++k2) {
                float2 hk = *(const float2*)&hs[k2 * 2];
                half8 w = wp[(size_t)k2 * 512];
                z0 += hk.x * (float)w[0] + hk.y * (float)w[1];
                z1 += hk.x * (float)w[2] + hk.y * (float)w[3];
                z2 += hk.x * (float)w[4] + hk.y * (float)w[5];
                z3 += hk.x * (float)w[6] + hk.y * (float)w[7];
            }
        }
        float ig = 1.f / (1.f + __expf(-z0));
        float fg = 1.f / (1.f + __expf(-z1));
        float gg = 1.f - 2.f / (1.f + __expf(2.f * z2));
        float og = 1.f / (1.f + __expf(-z3));
        c = fg * c + ig * gg;
        float tc = 1.f - 2.f / (1.f + __expf(2.f * c));
        float h = og * tc;
        __syncthreads();                                // all reads of old hs done
        hs[j] = h;
        ys[((size_t)(t * B_ + b)) * H_ + j] = h;
    }
    out[b * H_ + j] = c;
    out[B_ * H_ + b * H_ + j] = hs[j];
}

// ---------- fallback: all-f32 fused (used only if workspace too small) ----------
__global__ __launch_bounds__(512) void lstm_fb(const float* __restrict__ ins,
                                               const int* __restrict__ resets,
                                               const float* __restrict__ c0,
                                               const float* __restrict__ h0,
                                               const float* __restrict__ Wi,
                                               const float* __restrict__ Wh,
                                               const float* __restrict__ bv,
                                               float* __restrict__ out) {
    const int b = blockIdx.x;
    const int j = threadIdx.x;
    __shared__ float hs[H_];
    __shared__ float xs[D_];

    float c = c0[b * H_ + j];
    hs[j] = h0[b * H_ + j];
    const float b0 = bv[j], b1 = bv[H_ + j], b2 = bv[2 * H_ + j], b3 = bv[3 * H_ + j];
    float* ys = out + 2 * B_ * H_;

    for (int t = 0; t < T_; ++t) {
        __syncthreads();
        xs[j] = ins[((size_t)(t * B_ + b)) * D_ + j];
        __syncthreads();
        const bool rst = resets[t * B_ + b] != 0;
        float z0 = b0, z1 = b1, z2 = b2, z3 = b3;
        for (int k = 0; k < D_; ++k) {
            float xk = xs[k];
            z0 += xk * Wi[(size_t)k * N4H + j];
            z1 += xk * Wi[(size_t)k * N4H + H_ + j];
            z2 += xk * Wi[(size_t)k * N4H + 2 * H_ + j];
            z3 += xk * Wi[(size_t)k * N4H + 3 * H_ + j];
        }
        if (rst) {
            c = 0.f;
        } else {
            for (int k = 0; k < H_; ++k) {
                float hk = hs[k];
                z0 += hk * Wh[(size_t)k * N4H + j];
                z1 += hk * Wh[(size_t)k * N4H + H_ + j];
                z2 += hk * Wh[(size_t)k * N4H + 2 * H_ + j];
                z3 += hk * Wh[(size_t)k * N4H + 3 * H_ + j];
            }
        }
        float ig = 1.f / (1.f + __expf(-z0));
        float fg = 1.f / (1.f + __expf(-z1));
        float gg = 1.f - 2.f / (1.f + __expf(2.f * z2));
        float og = 1.f / (1.f + __expf(-z3));
        c = fg * c + ig * gg;
        float tc = 1.f - 2.f / (1.f + __expf(2.f * c));
        float h = og * tc;
        __syncthreads();
        hs[j] = h;
        ys[((size_t)(t * B_ + b)) * H_ + j] = h;
    }
    out[b * H_ + j] = c;
    out[B_ * H_ + b * H_ + j] = hs[j];
}

extern "C" void kernel_launch(void* const* d_in, const int* in_sizes, int n_in,
                              void* d_out, int out_size, void* d_ws, size_t ws_size,
                              hipStream_t stream) {
    const float* ins    = (const float*)d_in[0];
    const int*   resets = (const int*)d_in[1];
    const float* c0     = (const float*)d_in[2];
    const float* h0     = (const float*)d_in[3];
    const float* Wi     = (const float*)d_in[4];
    const float* Wh     = (const float*)d_in[5];
    const float* bv     = (const float*)d_in[6];
    float*       out    = (float*)d_out;

    const size_t offXH  = 0;
    const size_t offWiT = offXH  + (size_t)T_ * B_ * D_ * 2;   // ins as f16
    const size_t offWhP = offWiT + (size_t)D_ * N4H * 2;       // WiT f16
    const size_t offZ   = offWhP + (size_t)H_ * N4H * 2;       // WhP f16
    const size_t need   = offZ   + (size_t)T_ * B_ * N4H * 2;  // Z f16

    if (ws_size >= need) {
        _Float16* XH  = (_Float16*)((char*)d_ws + offXH);
        _Float16* WiT = (_Float16*)((char*)d_ws + offWiT);
        _Float16* WhP = (_Float16*)((char*)d_ws + offWhP);
        _Float16* Zs  = (_Float16*)((char*)d_ws + offZ);

        cvt_ins<<<(T_ * B_ * D_ / 4) / 256, 256, 0, stream>>>(ins, XH);
        cvt_wi <<<(D_ * N4H) / 256,        256, 0, stream>>>(Wi, WiT);
        cvt_wh <<<(H_ * N4H) / 256,        256, 0, stream>>>(Wh, WhP);
        gemm_xwi<<<dim3(T_ * B_ / 128, N4H / 128), 256, 0, stream>>>(XH, WiT, Zs);
        lstm_scan<<<B_, H_, 0, stream>>>(Zs, WhP, bv, resets, c0, h0, out);
    } else {
        lstm_fb<<<B_, H_, 0, stream>>>(ins, resets, c0, h0, Wi, Wh, bv, out);
    }
}